// Round 8
// baseline (1030.118 us; speedup 1.0000x reference)
//
#include <hip/hip_runtime.h>
#include <math.h>

#define BATCH 64
#define NTOK  729
#define DIM   64
#define NROWS 46656   // BATCH*NTOK

// ---------------------------------------------------------------------------
// Direct 3x3 SAME conv, NCHW, 27x27 spatial. v5:
// v4's 2-row x 3-px mapping (best FMA fraction) at 128 threads / 8 couts
// -> grid 1024 = 4 blocks/CU (R6 showed 2 blocks/CU -> 45% VALUBusy: staging
// phases can't overlap). Summation order per output unchanged vs v3/v4
// -> bitwise identical results.
// Block: 128 threads; tid<126 active = 13.5 row-pairs x 9 x-triples.
// Output: partial buffer [slab][B][Cout][729].
// ---------------------------------------------------------------------------
#define SROW 33
#define SCH  (29 * SROW)   // 957 floats per staged channel

template<int CIN_CHUNK, bool BN_IN>
__global__ __launch_bounds__(128) void conv3x3_v5(
    const float* __restrict__ in, const float* __restrict__ wgt,
    const float* __restrict__ scsh, float* __restrict__ outp,
    int Cin, int Cout, int cinPerSlab, int nslab)
{
  int groups = Cout / 8;
  int blocksPerB = groups * nslab;
  int b = blockIdx.x / blocksPerB;
  int rr = blockIdx.x % blocksPerB;
  int g = rr / nslab;
  int slab = rr % nslab;
  int c_begin = slab * cinPerSlab;
  int c_end = c_begin + cinPerSlab; if (c_end > Cin) c_end = Cin;

  __shared__ float s_in[CIN_CHUNK * SCH + SROW];   // +1 pad row for row-pair reads
  __shared__ float s_w[8 * CIN_CHUNK * 12];        // stride 12 -> 16B aligned
  __shared__ float s_sc[CIN_CHUNK];
  __shared__ float s_sh[CIN_CHUNK];

  const int tid = threadIdx.x;
  const bool active = tid < 126;
  const int rp = tid / 9;            // 0..13
  const int py = 2 * rp;             // 0,2,...,26
  const int px3 = (tid % 9) * 3;
  const bool row2ok = (py + 1) < 27;

  float acc[8][2][3];
  #pragma unroll
  for (int t = 0; t < 8; ++t)
    #pragma unroll
    for (int rI = 0; rI < 2; ++rI) { acc[t][rI][0]=0.f; acc[t][rI][1]=0.f; acc[t][rI][2]=0.f; }

  const size_t inB = (size_t)b * Cin;

  for (int c0 = c_begin; c0 < c_end; c0 += CIN_CHUNK) {
    int ccn = c_end - c0; if (ccn > CIN_CHUNK) ccn = CIN_CHUNK;
    if (BN_IN && tid < ccn) {
      s_sc[tid] = scsh[c0 + tid];
      s_sh[tid] = scsh[Cin + c0 + tid];
    }
    __syncthreads();   // protects s_in/s_w from previous iteration's readers
    for (int i = tid; i < CIN_CHUNK * SCH; i += 128) {
      int cc = i / SCH; int r2 = i - cc * SCH; int y = r2 / SROW; int x2 = r2 - y * SROW;
      float v = 0.f;
      if (cc < ccn && y >= 1 && y <= 27 && x2 >= 1 && x2 <= 27) {
        v = in[(inB + (c0 + cc)) * 729 + (y - 1) * 27 + (x2 - 1)];
        if (BN_IN) v = fmaxf(fmaf(v, s_sc[cc], s_sh[cc]), 0.f);
      }
      s_in[i] = v;
    }
    for (int i = tid; i < 8 * CIN_CHUNK * 9; i += 128) {
      int t = i / (CIN_CHUNK * 9); int r2 = i - t * CIN_CHUNK * 9;
      int cc = r2 / 9; int k = r2 - cc * 9;
      float wv = 0.f;
      if (cc < ccn) wv = wgt[((size_t)(g * 8 + t) * Cin + (c0 + cc)) * 9 + k];
      s_w[(t * CIN_CHUNK + cc) * 12 + k] = wv;
    }
    __syncthreads();
    if (active) {
      #pragma unroll 1
      for (int cc = 0; cc < ccn; ++cc) {
        const float* bp = &s_in[cc * SCH + py * SROW + px3];
        float r0[5], r1[5], r2[5], r3[5];
        #pragma unroll
        for (int j = 0; j < 5; ++j) {
          r0[j] = bp[j];
          r1[j] = bp[SROW + j];
          r2[j] = bp[2*SROW + j];
          r3[j] = bp[3*SROW + j];   // for py=26 this is the pad row; result discarded
        }
        #pragma unroll
        for (int t = 0; t < 8; ++t) {
          const int wb = (t * CIN_CHUNK + cc) * 12;
          const float4 wa = *(const float4*)&s_w[wb];
          const float4 wc = *(const float4*)&s_w[wb + 4];
          const float  w8 = s_w[wb + 8];
          #pragma unroll
          for (int p = 0; p < 3; ++p) {
            acc[t][0][p] += wa.x*r0[p]+wa.y*r0[p+1]+wa.z*r0[p+2]
                          + wa.w*r1[p]+wc.x*r1[p+1]+wc.y*r1[p+2]
                          + wc.z*r2[p]+wc.w*r2[p+1]+w8*r2[p+2];
            acc[t][1][p] += wa.x*r1[p]+wa.y*r1[p+1]+wa.z*r1[p+2]
                          + wa.w*r2[p]+wc.x*r2[p+1]+wc.y*r2[p+2]
                          + wc.z*r3[p]+wc.w*r3[p+1]+w8*r3[p+2];
          }
        }
      }
    }
  }
  if (active) {
    #pragma unroll
    for (int t = 0; t < 8; ++t) {
      size_t base = (((size_t)slab * BATCH + b) * Cout + (g * 8 + t)) * 729 + py * 27 + px3;
      outp[base+0]=acc[t][0][0]; outp[base+1]=acc[t][0][1]; outp[base+2]=acc[t][0][2];
      if (row2ok) {
        outp[base+27]=acc[t][1][0]; outp[base+28]=acc[t][1][1]; outp[base+29]=acc[t][1][2];
      }
    }
  }
}

// ---------------------------------------------------------------------------
__global__ __launch_bounds__(256) void conv_reduce_stats(
    const float* __restrict__ part, const float* __restrict__ bias,
    float* __restrict__ outp, double* __restrict__ stats, int C, int nslab)
{
  int b = blockIdx.x / C;
  int c = blockIdx.x % C;
  size_t slabStride = (size_t)BATCH * C * 729;
  size_t base = ((size_t)b * C + c) * 729;
  float bv = bias[c];
  float bsum = 0.f, bsq = 0.f;
  for (int e = threadIdx.x; e < 729; e += 256) {
    float v = bv;
    for (int s = 0; s < nslab; ++s) v += part[s*slabStride + base + e];
    outp[base + e] = v;
    bsum += v; bsq += v*v;
  }
  #pragma unroll
  for (int off = 32; off > 0; off >>= 1) {
    bsum += __shfl_down(bsum, off);
    bsq  += __shfl_down(bsq, off);
  }
  __shared__ float rs[4], rq[4];
  int wid = threadIdx.x >> 6;
  if ((threadIdx.x & 63) == 0) { rs[wid] = bsum; rq[wid] = bsq; }
  __syncthreads();
  if (threadIdx.x == 0) {
    float s1 = rs[0]+rs[1]+rs[2]+rs[3];
    float q1 = rq[0]+rq[1]+rq[2]+rq[3];
    atomicAdd(&stats[c], (double)s1);
    atomicAdd(&stats[C + c], (double)q1);
  }
}

__global__ void bn_finalize(const double* __restrict__ stats,
                            const float* __restrict__ gamma, const float* __restrict__ beta,
                            float* __restrict__ scsh, int C, float invCount)
{
  int c = threadIdx.x + blockIdx.x * blockDim.x; if (c >= C) return;
  double mu = stats[c] * (double)invCount;
  double var = stats[C + c] * (double)invCount - mu * mu;
  float rstd = (float)(1.0 / sqrt(var + 1e-5));
  float sc = gamma[c] * rstd;
  scsh[c] = sc;
  scsh[C + c] = beta[c] - (float)mu * sc;
}

// ---------------------------------------------------------------------------
// BN+ReLU conv3 output and transpose [B,64,729] -> t [B,729,64]; also xx[b,n].
// ---------------------------------------------------------------------------
__global__ __launch_bounds__(256) void bn_transpose_xx(
    const float* __restrict__ c3, const float* __restrict__ scsh,
    float* __restrict__ t, float* __restrict__ xx)
{
  int lb = (blockIdx.x & 7) * 96 + (blockIdx.x >> 3);   // 768 % 8 == 0, bijective
  int b = lb / 12, nt = lb % 12, n0 = nt * 64;
  __shared__ float s[64 * 65];
  for (int i = threadIdx.x; i < 4096; i += 256) {
    int d = i >> 6, j = i & 63; int n = n0 + j;
    float v = 0.f;
    if (n < 729) {
      v = c3[((size_t)b * 64 + d) * 729 + n];
      v = fmaxf(fmaf(v, scsh[d], scsh[64 + d]), 0.f);
    }
    s[d * 65 + j] = v;
  }
  __syncthreads();
  for (int i = threadIdx.x; i < 4096; i += 256) {
    int j = i >> 6, d = i & 63; int n = n0 + j;
    if (n < 729) t[((size_t)b * 729 + n) * 64 + d] = s[d * 65 + j];
  }
  if (threadIdx.x < 64) {
    int j = threadIdx.x; int n = n0 + j;
    if (n < 729) {
      float sm = 0.f;
      #pragma unroll
      for (int d = 0; d < 64; ++d) { float v = s[d * 65 + j]; sm += v * v; }
      xx[b * 729 + n] = sm;
    }
  }
}

// ---------------------------------------------------------------------------
// hs = t @ w_self, hw = t @ w_nb. (R5-proven)
// ---------------------------------------------------------------------------
__global__ __launch_bounds__(256) void gemm_selfnb(
    const float* __restrict__ t, const float* __restrict__ wself,
    const float* __restrict__ wnb, float* __restrict__ hs, float* __restrict__ hw)
{
  int lb = (blockIdx.x & 7) * 96 + (blockIdx.x >> 3);
  int b = lb / 12, nt = lb % 12, n0 = nt * 64;
  __shared__ __align__(16) float s_tT[64 * 68];
  __shared__ __align__(16) float s_a[64 * 68];
  __shared__ __align__(16) float s_b[64 * 68];
  const int tid = threadIdx.x;
  for (int i = tid; i < 1024; i += 256) {
    int n = i >> 4, dq = i & 15;
    float4 v = make_float4(0.f, 0.f, 0.f, 0.f);
    if (n0 + n < 729) v = *(const float4*)&t[((size_t)b * 729 + n0 + n) * 64 + 4 * dq];
    s_tT[(4*dq+0)*68 + n] = v.x;
    s_tT[(4*dq+1)*68 + n] = v.y;
    s_tT[(4*dq+2)*68 + n] = v.z;
    s_tT[(4*dq+3)*68 + n] = v.w;
  }
  for (int i = tid; i < 1024; i += 256) {
    int d = i >> 4, jq = i & 15;
    *(float4*)&s_a[d*68 + 4*jq] = *(const float4*)&wself[d*64 + 4*jq];
    *(float4*)&s_b[d*68 + 4*jq] = *(const float4*)&wnb[d*64 + 4*jq];
  }
  __syncthreads();
  int ty = tid >> 4, tx = tid & 15;
  float acc0[4][4], acc1[4][4];
  #pragma unroll
  for (int i = 0; i < 4; ++i)
    #pragma unroll
    for (int j = 0; j < 4; ++j) { acc0[i][j] = 0.f; acc1[i][j] = 0.f; }
  #pragma unroll 8
  for (int d = 0; d < 64; ++d) {
    float4 av = *(const float4*)&s_tT[d*68 + 4*ty];
    float4 b1 = *(const float4*)&s_a[d*68 + 4*tx];
    float4 b2 = *(const float4*)&s_b[d*68 + 4*tx];
    float a[4] = {av.x, av.y, av.z, av.w};
    float u[4] = {b1.x, b1.y, b1.z, b1.w};
    float w[4] = {b2.x, b2.y, b2.z, b2.w};
    #pragma unroll
    for (int i = 0; i < 4; ++i)
      #pragma unroll
      for (int j = 0; j < 4; ++j) { acc0[i][j] += a[i]*u[j]; acc1[i][j] += a[i]*w[j]; }
  }
  #pragma unroll
  for (int i = 0; i < 4; ++i) {
    int n = n0 + 4*ty + i;
    if (n < 729) {
      size_t o = ((size_t)b * 729 + n) * 64 + 4*tx;
      *(float4*)&hs[o] = make_float4(acc0[i][0], acc0[i][1], acc0[i][2], acc0[i][3]);
      *(float4*)&hw[o] = make_float4(acc1[i][0], acc1[i][1], acc1[i][2], acc1[i][3]);
    }
  }
}

// ---------------------------------------------------------------------------
// kNN v3: 2x8 register tile. A-frag b64 / B-frag b128 are 8-lane broadcasts
// (320B distinct per wave-d-iter vs 2KB in v2). Top-8 per (thread,row) kept in
// REGISTERS (no s_S, no scan barriers); m-tiles double-buffered with
// async-stage split -> 1 barrier per tile. Final per-row 8-list merge.
// Ranking: (xx[m]-2*dot, idx) lexicographic == stable top_k of clamped dist.
// ---------------------------------------------------------------------------
__global__ __launch_bounds__(256) void dist_topk(
    const float* __restrict__ t, const float* __restrict__ xx, int* __restrict__ nbr)
{
  int lb = (blockIdx.x & 7) * 96 + (blockIdx.x >> 3);
  int b = lb / 12, nt = lb % 12, n0 = nt * 64;
  __shared__ __align__(16) float s_nT[64 * 68];
  __shared__ __align__(16) float s_m0[64 * 68];
  __shared__ __align__(16) float s_m1[64 * 68];

  const int tid = threadIdx.x;
  const int rg = tid >> 3;            // 0..31 -> rows 2rg, 2rg+1
  const int cg = tid & 7;             // cols 8cg..8cg+7
  const int r0 = 2 * rg, r1 = r0 + 1;
  const int self0 = n0 + r0, self1 = n0 + r1;
  const size_t tb = (size_t)b * 729;
  const float* xxb = &xx[b * 729];

  float kv0[8], kv1[8]; int ki0[8], ki1[8];
  #pragma unroll
  for (int i = 0; i < 8; ++i) {
    kv0[i] = 3.0e38f; ki0[i] = 0x7fffffff;
    kv1[i] = 3.0e38f; ki1[i] = 0x7fffffff;
  }

  // stage n-tile transposed
  for (int i = tid; i < 1024; i += 256) {
    int n = i >> 4, dq = i & 15;
    float4 v = make_float4(0.f, 0.f, 0.f, 0.f);
    if (n0 + n < 729) v = *(const float4*)&t[(tb + n0 + n) * 64 + 4 * dq];
    s_nT[(4*dq+0)*68 + n] = v.x;
    s_nT[(4*dq+1)*68 + n] = v.y;
    s_nT[(4*dq+2)*68 + n] = v.z;
    s_nT[(4*dq+3)*68 + n] = v.w;
  }
  // stage m-tile 0 transposed (fully valid)
  for (int i = tid; i < 1024; i += 256) {
    int m = i >> 4, dq = i & 15;
    float4 v = *(const float4*)&t[(tb + m) * 64 + 4 * dq];
    s_m0[(4*dq+0)*68 + m] = v.x;
    s_m0[(4*dq+1)*68 + m] = v.y;
    s_m0[(4*dq+2)*68 + m] = v.z;
    s_m0[(4*dq+3)*68 + m] = v.w;
  }
  __syncthreads();

  for (int mt = 0; mt < 12; ++mt) {
    const int m0 = mt * 64;
    const float* cur = (mt & 1) ? s_m1 : s_m0;
    float*       nxt = (mt & 1) ? s_m0 : s_m1;

    // issue next-tile + xm loads early (hidden under GEMM)
    float4 st[4];
    if (mt < 11) {
      #pragma unroll
      for (int j = 0; j < 4; ++j) {
        int i = tid + 256 * j; int m = i >> 4, dq = i & 15;
        int mm = m0 + 64 + m;
        st[j] = (mm < 729) ? *(const float4*)&t[(tb + mm) * 64 + 4 * dq]
                           : make_float4(0.f, 0.f, 0.f, 0.f);
      }
    }
    float xm[8];
    #pragma unroll
    for (int k = 0; k < 8; ++k) {
      // scalar loads (xx rows are odd-strided, no 16B align); reads past
      // 729 stay inside ws (stats region) and are filtered by `valid`.
      xm[k] = xxb[m0 + 8*cg + k];
    }

    // GEMM 2x8: per d, b64 A-frag + 2x b128 B-frag (all 8-lane broadcast)
    float acc0[8], acc1[8];
    #pragma unroll
    for (int j = 0; j < 8; ++j) { acc0[j] = 0.f; acc1[j] = 0.f; }
    #pragma unroll 4
    for (int d = 0; d < 64; ++d) {
      float2 a  = *(const float2*)&s_nT[d*68 + r0];
      float4 bA = *(const float4*)&cur[d*68 + 8*cg];
      float4 bB = *(const float4*)&cur[d*68 + 8*cg + 4];
      float bb[8] = {bA.x, bA.y, bA.z, bA.w, bB.x, bB.y, bB.z, bB.w};
      #pragma unroll
      for (int j = 0; j < 8; ++j) {
        acc0[j] += a.x * bb[j];
        acc1[j] += a.y * bb[j];
      }
    }

    // register-local streaming top-8 per row
    #pragma unroll
    for (int k = 0; k < 8; ++k) {
      int m = m0 + 8*cg + k;
      bool inb = (m < 729);
      {
        float sv = fmaf(-2.f, acc0[k], xm[k]);
        bool lt = inb && (m != self0) &&
                  ((sv < kv0[7]) || (sv == kv0[7] && m < ki0[7]));
        if (lt) {
          float cv = sv; int ci = m;
          #pragma unroll
          for (int ii = 0; ii < 8; ++ii) {
            bool less = (cv < kv0[ii]) || (cv == kv0[ii] && ci < ki0[ii]);
            float tv = less ? kv0[ii] : cv; int ti = less ? ki0[ii] : ci;
            kv0[ii] = less ? cv : kv0[ii]; ki0[ii] = less ? ci : ki0[ii];
            cv = tv; ci = ti;
          }
        }
      }
      {
        float sv = fmaf(-2.f, acc1[k], xm[k]);
        bool lt = inb && (m != self1) &&
                  ((sv < kv1[7]) || (sv == kv1[7] && m < ki1[7]));
        if (lt) {
          float cv = sv; int ci = m;
          #pragma unroll
          for (int ii = 0; ii < 8; ++ii) {
            bool less = (cv < kv1[ii]) || (cv == kv1[ii] && ci < ki1[ii]);
            float tv = less ? kv1[ii] : cv; int ti = less ? ki1[ii] : ci;
            kv1[ii] = less ? cv : kv1[ii]; ki1[ii] = less ? ci : ki1[ii];
            cv = tv; ci = ti;
          }
        }
      }
    }

    // write staged regs into nxt buffer
    if (mt < 11) {
      #pragma unroll
      for (int j = 0; j < 4; ++j) {
        int i = tid + 256 * j; int m = i >> 4, dq = i & 15;
        nxt[(4*dq+0)*68 + m] = st[j].x;
        nxt[(4*dq+1)*68 + m] = st[j].y;
        nxt[(4*dq+2)*68 + m] = st[j].z;
        nxt[(4*dq+3)*68 + m] = st[j].w;
      }
    }
    __syncthreads();   // nxt staged; cur free for overwrite next iter
  }

  // merge the 8 per-thread lists per row (reuse s_m0 = vals, s_m1 = idx)
  float* mv = s_m0;
  int*   mi = (int*)s_m1;
  #pragma unroll
  for (int k = 0; k < 8; ++k) {
    mv[r0*68 + cg*8 + k] = kv0[k]; mi[r0*68 + cg*8 + k] = ki0[k];
    mv[r1*68 + cg*8 + k] = kv1[k]; mi[r1*68 + cg*8 + k] = ki1[k];
  }
  __syncthreads();
  if (tid < 64) {
    int n = n0 + tid;
    if (n < 729) {
      int rb = tid * 68;
      int p[8] = {0,0,0,0,0,0,0,0};
      int* op = &nbr[((size_t)b * 729 + n) * 8];
      for (int o = 0; o < 8; ++o) {
        float bvv = 3.5e38f; int bii = 0x7fffffff; int bq = 0;
        #pragma unroll
        for (int q = 0; q < 8; ++q) {          // constant-indexed p[q] -> regs
          float v = mv[rb + q*8 + p[q]]; int ii = mi[rb + q*8 + p[q]];
          if (v < bvv || (v == bvv && ii < bii)) { bvv = v; bii = ii; bq = q; }
        }
        #pragma unroll
        for (int q = 0; q < 8; ++q) p[q] += (bq == q);
        op[o] = bii;
      }
    }
  }
}

// ---------------------------------------------------------------------------
__global__ __launch_bounds__(256) void gkan_kernel(
    const float* __restrict__ hs, const float* __restrict__ hw,
    const int* __restrict__ nbr, const float* __restrict__ bias,
    const float* __restrict__ kan_a, const float* __restrict__ kan_b,
    float* __restrict__ gpre)
{
  int row = blockIdx.x * 4 + (threadIdx.x >> 6);
  int d = threadIdx.x & 63;
  float degf = 8.0f + 1e-6f;
  float coef = 1.0f / degf;
  size_t bbase = (size_t)(row / 729) * 729;
  float v = hs[(size_t)row * 64 + d] + hw[(size_t)row * 64 + d] + bias[d];
  float nsum = 0.f;
  #pragma unroll
  for (int j = 0; j < 8; ++j) {
    int m = nbr[(size_t)row * 8 + j];
    nsum += hw[(bbase + m) * 64 + d];
  }
  v += coef * nsum;
  float a0 = kan_a[d*3], a1 = kan_a[d*3+1], a2 = kan_a[d*3+2];
  float b0 = kan_b[d*2], b1 = kan_b[d*2+1];
  float v2 = v * v;
  float num = a0 + a1*v + a2*v2;
  float den = 1.f + fabsf(b0*v + b1*v2);
  gpre[(size_t)row * 64 + d] = num / (den + 1e-8f);
}

__global__ __launch_bounds__(256) void stats_tok(
    const float* __restrict__ g, double* __restrict__ stats)
{
  int d = threadIdx.x & 63, qq = threadIdx.x >> 6;
  int r0 = blockIdx.x * 183;
  int rend = r0 + 183; if (rend > NROWS) rend = NROWS;
  float sm = 0.f, sq = 0.f;
  for (int r = r0 + qq; r < rend; r += 4) {
    float v = g[(size_t)r * 64 + d];
    sm += v; sq += v * v;
  }
  __shared__ float ls[256], lq[256];
  ls[threadIdx.x] = sm; lq[threadIdx.x] = sq;
  __syncthreads();
  if (threadIdx.x < 64) {
    sm = ls[d] + ls[64+d] + ls[128+d] + ls[192+d];
    sq = lq[d] + lq[64+d] + lq[128+d] + lq[192+d];
    atomicAdd(&stats[d], (double)sm);
    atomicAdd(&stats[64 + d], (double)sq);
  }
}

// ---------------------------------------------------------------------------
__global__ __launch_bounds__(256) void fuzzy_attn(
    const float* __restrict__ gpre, const float* __restrict__ scshG,
    const float* __restrict__ centers, const float* __restrict__ gam,
    const float* __restrict__ w1, const float* __restrict__ b1,
    const float* __restrict__ w2, const float* __restrict__ b2,
    float* __restrict__ g2)
{
  int wv = threadIdx.x >> 6, d = threadIdx.x & 63;
  int row = blockIdx.x * 4 + wv;
  __shared__ float s_rbf[4][64];
  __shared__ float s_a1[4][16];
  float v = gpre[(size_t)row * 64 + d];
  float gn = fmaf(v, scshG[d], scshG[64 + d]);
  float acc = 0.f;
  #pragma unroll
  for (int f = 0; f < 9; ++f) {
    float dc = gn - centers[d*9 + f];
    acc += expf(-fabsf(gam[d*9 + f]) * dc * dc);
  }
  s_rbf[wv][d] = acc + 9e-10f;
  __syncthreads();
  if (d < 16) {
    float a = b1[d];
    #pragma unroll 8
    for (int k = 0; k < 64; ++k) a += w1[d*64 + k] * s_rbf[wv][k];
    s_a1[wv][d] = fmaxf(a, 0.f);
  }
  __syncthreads();
  float a2 = b2[d];
  #pragma unroll
  for (int i = 0; i < 16; ++i) a2 += w2[d*16 + i] * s_a1[wv][i];
  float sig = 1.f / (1.f + expf(-a2));
  g2[(size_t)row * 64 + d] = gn * (1.f + sig);
}

__global__ __launch_bounds__(256) void pool_kernel(
    const float* __restrict__ g2, const float* __restrict__ scshF, float* __restrict__ p)
{
  int b = blockIdx.x;
  int d = threadIdx.x & 63, qq = threadIdx.x >> 6;
  float sc = scshF[d], sh = scshF[64 + d];
  float sm = 0.f, mx = -3.0e38f;
  for (int n = qq; n < 729; n += 4) {
    float v = fmaf(g2[((size_t)b * 729 + n) * 64 + d], sc, sh);
    sm += v; mx = fmaxf(mx, v);
  }
  __shared__ float ls[256], lm[256];
  ls[threadIdx.x] = sm; lm[threadIdx.x] = mx;
  __syncthreads();
  if (threadIdx.x < 64) {
    sm = ls[d] + ls[64+d] + ls[128+d] + ls[192+d];
    mx = fmaxf(fmaxf(lm[d], lm[64+d]), fmaxf(lm[128+d], lm[192+d]));
    p[b * 64 + d] = 0.5f * (sm / 729.f) + 0.5f * mx;
  }
}

__global__ __launch_bounds__(256) void classifier(
    const float* __restrict__ p, const float* __restrict__ f1w, const float* __restrict__ f1b,
    const float* __restrict__ bng, const float* __restrict__ bnb,
    const float* __restrict__ f2w, const float* __restrict__ f2b, float* __restrict__ outp)
{
  __shared__ float s_p[64 * 64];
  __shared__ float s_c[64 * 128];
  __shared__ float s_sc[128], s_sh[128];
  for (int i = threadIdx.x; i < 4096; i += 256) s_p[i] = p[i];
  __syncthreads();
  for (int o = threadIdx.x; o < 8192; o += 256) {
    int b = o >> 7, h = o & 127;
    float acc = f1b[h];
    #pragma unroll 8
    for (int d = 0; d < 64; ++d) acc += s_p[b*64 + d] * f1w[h*64 + d];
    s_c[o] = acc;
  }
  __syncthreads();
  if (threadIdx.x < 128) {
    int h = threadIdx.x;
    float sm = 0.f, sq = 0.f;
    for (int b = 0; b < 64; ++b) { float v = s_c[b*128 + h]; sm += v; sq += v*v; }
    float mu = sm / 64.f;
    float var = sq / 64.f - mu * mu;
    float rstd = rsqrtf(var + 1e-5f);
    float sc = bng[h] * rstd;
    s_sc[h] = sc; s_sh[h] = bnb[h] - mu * sc;
  }
  __syncthreads();
  for (int o = threadIdx.x; o < 1024; o += 256) {
    int b = o >> 4, j = o & 15;
    float acc = f2b[j];
    #pragma unroll 8
    for (int h = 0; h < 128; ++h) {
      float v = fmaxf(fmaf(s_c[b*128 + h], s_sc[h], s_sh[h]), 0.f);
      acc += f2w[j*128 + h] * v;
    }
    outp[o] = acc;
  }
}

// ---------------------------------------------------------------------------
extern "C" void kernel_launch(void* const* d_in, const int* in_sizes, int n_in,
                              void* d_out, int out_size, void* d_ws, size_t ws_size,
                              hipStream_t stream)
{
  const float* x      = (const float*)d_in[0];
  const float* c1w    = (const float*)d_in[1];
  const float* c1b    = (const float*)d_in[2];
  const float* bn1g   = (const float*)d_in[3];
  const float* bn1b   = (const float*)d_in[4];
  const float* c2wt   = (const float*)d_in[5];
  const float* c2b    = (const float*)d_in[6];
  const float* bn2g   = (const float*)d_in[7];
  const float* bn2b   = (const float*)d_in[8];
  const float* c3wt   = (const float*)d_in[9];
  const float* c3b    = (const float*)d_in[10];
  const float* bn3g   = (const float*)d_in[11];
  const float* bn3b   = (const float*)d_in[12];
  const float* wself  = (const float*)d_in[13];
  const float* wnb    = (const float*)d_in[14];
  const float* gbias  = (const float*)d_in[15];
  const float* kana   = (const float*)d_in[16];
  const float* kanb   = (const float*)d_in[17];
  const float* gbng   = (const float*)d_in[18];
  const float* gbnb   = (const float*)d_in[19];
  const float* cent   = (const float*)d_in[20];
  const float* gamr   = (const float*)d_in[21];
  const float* aw1    = (const float*)d_in[22];
  const float* ab1    = (const float*)d_in[23];
  const float* aw2    = (const float*)d_in[24];
  const float* ab2    = (const float*)d_in[25];
  const float* fbng   = (const float*)d_in[26];
  const float* fbnb   = (const float*)d_in[27];
  const float* f1w    = (const float*)d_in[28];
  const float* f1b    = (const float*)d_in[29];
  const float* cbng   = (const float*)d_in[30];
  const float* cbnb   = (const float*)d_in[31];
  const float* f2w    = (const float*)d_in[32];
  const float* f2b    = (const float*)d_in[33];

  char* ws = (char*)d_ws;
  float*  P     = (float*) (ws + 0);          // 23,887,872 B (partial slabs)
  float*  c1    = (float*) (ws + 23887872);   //  5,971,968 B
  float*  c2    = (float*) (ws + 29859840);   // 11,943,936 B
  float*  c3    = (float*) (ws + 41803776);   // 11,943,936 B
  int*    nbr   = (int*)   (ws + 53747712);   //  1,492,992 B
  float*  xx    = (float*) (ws + 55240704);   //    186,624 B
  double* stats = (double*)(ws + 55427328);   //      4,608 B
  float*  scsh  = (float*) (ws + 55431936);   //      2,304 B
  float*  pbuf  = (float*) (ws + 55434240);   //     16,384 B
  // aliases (disjoint lifetimes on the serialized stream):
  float* hw   = P;
  float* t    = (float*)(ws + 11943936);      // inside P, after P dead
  float* hs   = c2;
  float* gpre = c3;
  float* g2   = t;

  hipMemsetAsync(stats, 0, 576 * sizeof(double), stream);

  const float inv = 1.0f / 46656.0f;

  // conv1: 4 groups x 4 slabs x 64 b = 1024 blocks of 128 (4 blocks/CU)
  conv3x3_v5<8,false><<<dim3(1024), dim3(128), 0, stream>>>(
      x,  c1w, nullptr, P, 200, 32, 50, 4);
  conv_reduce_stats<<<dim3(2048), dim3(256), 0, stream>>>(P, c1b, c1, stats, 32, 4);
  bn_finalize<<<dim3(1), dim3(32), 0, stream>>>(stats, bn1g, bn1b, scsh, 32, inv);
  // conv2: 8 groups x 2 slabs -> 1024 blocks
  conv3x3_v5<8,true><<<dim3(1024), dim3(128), 0, stream>>>(
      c1, c2wt, scsh, P, 32, 64, 16, 2);
  conv_reduce_stats<<<dim3(4096), dim3(256), 0, stream>>>(P, c2b, c2, stats + 64, 64, 2);
  bn_finalize<<<dim3(1), dim3(64), 0, stream>>>(stats + 64, bn2g, bn2b, scsh + 64, 64, inv);
  // conv3: 8 groups x 2 slabs -> 1024 blocks
  conv3x3_v5<8,true><<<dim3(1024), dim3(128), 0, stream>>>(
      c2, c3wt, scsh + 64, P, 64, 64, 32, 2);
  conv_reduce_stats<<<dim3(4096), dim3(256), 0, stream>>>(P, c3b, c3, stats + 192, 64, 2);
  bn_finalize<<<dim3(1), dim3(64), 0, stream>>>(stats + 192, bn3g, bn3b, scsh + 192, 64, inv);
  // tokens
  bn_transpose_xx<<<dim3(768), dim3(256), 0, stream>>>(c3, scsh + 192, t, xx);
  gemm_selfnb<<<dim3(768), dim3(256), 0, stream>>>(t, wself, wnb, hs, hw);
  dist_topk<<<dim3(768), dim3(256), 0, stream>>>(t, xx, nbr);
  gkan_kernel<<<dim3(11664), dim3(256), 0, stream>>>(hs, hw, nbr, gbias, kana, kanb, gpre);
  stats_tok<<<dim3(256), dim3(256), 0, stream>>>(gpre, stats + 320);
  bn_finalize<<<dim3(1), dim3(64), 0, stream>>>(stats + 320, gbng, gbnb, scsh + 320, 64, inv);
  fuzzy_attn<<<dim3(11664), dim3(256), 0, stream>>>(gpre, scsh + 320, cent, gamr, aw1, ab1, aw2, ab2, g2);
  stats_tok<<<dim3(256), dim3(256), 0, stream>>>(g2, stats + 448);
  bn_finalize<<<dim3(1), dim3(64), 0, stream>>>(stats + 448, fbng, fbnb, scsh + 448, 64, inv);
  pool_kernel<<<dim3(64), dim3(256), 0, stream>>>(g2, scsh + 448, pbuf);
  classifier<<<dim3(1), dim3(256), 0, stream>>>(pbuf, f1w, f1b, cbng, cbnb, f2w, f2b, (float*)d_out);
}

// Round 9
// 809.668 us; speedup vs baseline: 1.2723x; 1.2723x over previous
//
#include <hip/hip_runtime.h>
#include <math.h>

#define BATCH 64
#define NTOK  729
#define DIM   64
#define NROWS 46656   // BATCH*NTOK

// ---------------------------------------------------------------------------
// Direct 3x3 SAME conv, NCHW, 27x27 spatial. v6 = v4 structure (256 thr,
// 16 couts as 2 grps x 8, 2rows x 3px per thread: best measured 176us) plus:
//  - source-indexed coalesced staging (no bounds check; div 729/27 magic-mul)
//  - halo pre-zeroed ONCE (interior writes never touch halo)
//  - grid grown via nslab (host-adaptive on ws_size): 4 blocks/CU
// v5 lesson: couts/block amortizes staging; 8-cout blocks doubled staging
// traffic -> regression. Summation order per output unchanged -> same values.
// Output: partial buffer [slab][B][Cout][729].
// ---------------------------------------------------------------------------
#define SROW 33
#define SCH  (29 * SROW)   // 957 floats per staged channel

template<int CIN_CHUNK, bool BN_IN>
__global__ __launch_bounds__(256) void conv3x3_v6(
    const float* __restrict__ in, const float* __restrict__ wgt,
    const float* __restrict__ scsh, float* __restrict__ outp,
    int Cin, int Cout, int cinPerSlab, int nslab)
{
  int bigGroups = Cout / 16;
  int blocksPerB = bigGroups * nslab;
  int b = blockIdx.x / blocksPerB;
  int rr = blockIdx.x % blocksPerB;
  int bg = rr / nslab;
  int slab = rr % nslab;
  int c_begin = slab * cinPerSlab;
  int c_end = c_begin + cinPerSlab; if (c_end > Cin) c_end = Cin;

  __shared__ float s_in[CIN_CHUNK * SCH + SROW];   // +1 pad row for row-pair reads
  __shared__ float s_w[16 * CIN_CHUNK * 12];       // stride 12 -> 16B aligned
  __shared__ float s_sc[CIN_CHUNK];
  __shared__ float s_sh[CIN_CHUNK];

  const int tid = threadIdx.x;
  const int grp = tid >> 7;          // 0: couts +0..7, 1: couts +8..15
  const int idx = tid & 127;
  const bool active = idx < 126;
  const int rp = idx / 9;            // 0..13
  const int py = 2 * rp;             // 0,2,...,26
  const int px3 = (idx % 9) * 3;
  const bool row2ok = (py + 1) < 27;

  float acc[8][2][3];
  #pragma unroll
  for (int t = 0; t < 8; ++t)
    #pragma unroll
    for (int rI = 0; rI < 2; ++rI) { acc[t][rI][0]=0.f; acc[t][rI][1]=0.f; acc[t][rI][2]=0.f; }

  const size_t inB = (size_t)b * Cin;

  // one-time zero: halo (and everything) - interior overwritten per chunk
  for (int i = tid; i < CIN_CHUNK * SCH + SROW; i += 256) s_in[i] = 0.f;

  for (int c0 = c_begin; c0 < c_end; c0 += CIN_CHUNK) {
    int ccn = c_end - c0; if (ccn > CIN_CHUNK) ccn = CIN_CHUNK;
    if (BN_IN && tid < ccn) {
      s_sc[tid] = scsh[c0 + tid];
      s_sh[tid] = scsh[Cin + c0 + tid];
    }
    __syncthreads();   // zero/prev-compute done; s_sc visible
    // interior staging: coalesced source order
    {
      const float* src = &in[(inB + c0) * 729];
      for (int i = tid; i < ccn * 729; i += 256) {
        int cc = i / 729; int rem = i - cc * 729;
        int y = rem / 27; int x = rem - y * 27;
        float v = src[i];
        if (BN_IN) v = fmaxf(fmaf(v, s_sc[cc], s_sh[cc]), 0.f);
        s_in[cc * SCH + (y + 1) * SROW + (x + 1)] = v;
      }
    }
    for (int i = tid; i < 16 * CIN_CHUNK * 9; i += 256) {
      int t = i / (CIN_CHUNK * 9); int r2 = i - t * CIN_CHUNK * 9;
      int cc = r2 / 9; int k = r2 - cc * 9;
      float wv = 0.f;
      if (cc < ccn) wv = wgt[((size_t)(bg * 16 + t) * Cin + (c0 + cc)) * 9 + k];
      s_w[(t * CIN_CHUNK + cc) * 12 + k] = wv;
    }
    __syncthreads();
    if (active) {
      #pragma unroll 1
      for (int cc = 0; cc < ccn; ++cc) {
        const float* bp = &s_in[cc * SCH + py * SROW + px3];
        float r0[5], r1[5], r2[5], r3[5];
        #pragma unroll
        for (int j = 0; j < 5; ++j) {
          r0[j] = bp[j];
          r1[j] = bp[SROW + j];
          r2[j] = bp[2*SROW + j];
          r3[j] = bp[3*SROW + j];   // for py=26 this is the pad row; result discarded
        }
        #pragma unroll
        for (int t = 0; t < 8; ++t) {
          const int wb = ((grp * 8 + t) * CIN_CHUNK + cc) * 12;
          const float4 wa = *(const float4*)&s_w[wb];
          const float4 wc = *(const float4*)&s_w[wb + 4];
          const float  w8 = s_w[wb + 8];
          #pragma unroll
          for (int p = 0; p < 3; ++p) {
            acc[t][0][p] += wa.x*r0[p]+wa.y*r0[p+1]+wa.z*r0[p+2]
                          + wa.w*r1[p]+wc.x*r1[p+1]+wc.y*r1[p+2]
                          + wc.z*r2[p]+wc.w*r2[p+1]+w8*r2[p+2];
            acc[t][1][p] += wa.x*r1[p]+wa.y*r1[p+1]+wa.z*r1[p+2]
                          + wa.w*r2[p]+wc.x*r2[p+1]+wc.y*r2[p+2]
                          + wc.z*r3[p]+wc.w*r3[p+1]+w8*r3[p+2];
          }
        }
      }
    }
  }
  if (active) {
    #pragma unroll
    for (int t = 0; t < 8; ++t) {
      size_t base = (((size_t)slab * BATCH + b) * Cout + (bg * 16 + grp * 8 + t)) * 729 + py * 27 + px3;
      outp[base+0]=acc[t][0][0]; outp[base+1]=acc[t][0][1]; outp[base+2]=acc[t][0][2];
      if (row2ok) {
        outp[base+27]=acc[t][1][0]; outp[base+28]=acc[t][1][1]; outp[base+29]=acc[t][1][2];
      }
    }
  }
}

// ---------------------------------------------------------------------------
__global__ __launch_bounds__(256) void conv_reduce_stats(
    const float* __restrict__ part, const float* __restrict__ bias,
    float* __restrict__ outp, double* __restrict__ stats, int C, int nslab)
{
  int b = blockIdx.x / C;
  int c = blockIdx.x % C;
  size_t slabStride = (size_t)BATCH * C * 729;
  size_t base = ((size_t)b * C + c) * 729;
  float bv = bias[c];
  float bsum = 0.f, bsq = 0.f;
  for (int e = threadIdx.x; e < 729; e += 256) {
    float v = bv;
    for (int s = 0; s < nslab; ++s) v += part[s*slabStride + base + e];
    outp[base + e] = v;
    bsum += v; bsq += v*v;
  }
  #pragma unroll
  for (int off = 32; off > 0; off >>= 1) {
    bsum += __shfl_down(bsum, off);
    bsq  += __shfl_down(bsq, off);
  }
  __shared__ float rs[4], rq[4];
  int wid = threadIdx.x >> 6;
  if ((threadIdx.x & 63) == 0) { rs[wid] = bsum; rq[wid] = bsq; }
  __syncthreads();
  if (threadIdx.x == 0) {
    float s1 = rs[0]+rs[1]+rs[2]+rs[3];
    float q1 = rq[0]+rq[1]+rq[2]+rq[3];
    atomicAdd(&stats[c], (double)s1);
    atomicAdd(&stats[C + c], (double)q1);
  }
}

__global__ void bn_finalize(const double* __restrict__ stats,
                            const float* __restrict__ gamma, const float* __restrict__ beta,
                            float* __restrict__ scsh, int C, float invCount)
{
  int c = threadIdx.x + blockIdx.x * blockDim.x; if (c >= C) return;
  double mu = stats[c] * (double)invCount;
  double var = stats[C + c] * (double)invCount - mu * mu;
  float rstd = (float)(1.0 / sqrt(var + 1e-5));
  float sc = gamma[c] * rstd;
  scsh[c] = sc;
  scsh[C + c] = beta[c] - (float)mu * sc;
}

// ---------------------------------------------------------------------------
// BN+ReLU conv3 output and transpose [B,64,729] -> t [B,729,64]; also xx[b,n].
// ---------------------------------------------------------------------------
__global__ __launch_bounds__(256) void bn_transpose_xx(
    const float* __restrict__ c3, const float* __restrict__ scsh,
    float* __restrict__ t, float* __restrict__ xx)
{
  int lb = (blockIdx.x & 7) * 96 + (blockIdx.x >> 3);   // 768 % 8 == 0, bijective
  int b = lb / 12, nt = lb % 12, n0 = nt * 64;
  __shared__ float s[64 * 65];
  for (int i = threadIdx.x; i < 4096; i += 256) {
    int d = i >> 6, j = i & 63; int n = n0 + j;
    float v = 0.f;
    if (n < 729) {
      v = c3[((size_t)b * 64 + d) * 729 + n];
      v = fmaxf(fmaf(v, scsh[d], scsh[64 + d]), 0.f);
    }
    s[d * 65 + j] = v;
  }
  __syncthreads();
  for (int i = threadIdx.x; i < 4096; i += 256) {
    int j = i >> 6, d = i & 63; int n = n0 + j;
    if (n < 729) t[((size_t)b * 729 + n) * 64 + d] = s[d * 65 + j];
  }
  if (threadIdx.x < 64) {
    int j = threadIdx.x; int n = n0 + j;
    if (n < 729) {
      float sm = 0.f;
      #pragma unroll
      for (int d = 0; d < 64; ++d) { float v = s[d * 65 + j]; sm += v * v; }
      xx[b * 729 + n] = sm;
    }
  }
}

// ---------------------------------------------------------------------------
// hs = t @ w_self, hw = t @ w_nb. (R5-proven)
// ---------------------------------------------------------------------------
__global__ __launch_bounds__(256) void gemm_selfnb(
    const float* __restrict__ t, const float* __restrict__ wself,
    const float* __restrict__ wnb, float* __restrict__ hs, float* __restrict__ hw)
{
  int lb = (blockIdx.x & 7) * 96 + (blockIdx.x >> 3);
  int b = lb / 12, nt = lb % 12, n0 = nt * 64;
  __shared__ __align__(16) float s_tT[64 * 68];
  __shared__ __align__(16) float s_a[64 * 68];
  __shared__ __align__(16) float s_b[64 * 68];
  const int tid = threadIdx.x;
  for (int i = tid; i < 1024; i += 256) {
    int n = i >> 4, dq = i & 15;
    float4 v = make_float4(0.f, 0.f, 0.f, 0.f);
    if (n0 + n < 729) v = *(const float4*)&t[((size_t)b * 729 + n0 + n) * 64 + 4 * dq];
    s_tT[(4*dq+0)*68 + n] = v.x;
    s_tT[(4*dq+1)*68 + n] = v.y;
    s_tT[(4*dq+2)*68 + n] = v.z;
    s_tT[(4*dq+3)*68 + n] = v.w;
  }
  for (int i = tid; i < 1024; i += 256) {
    int d = i >> 4, jq = i & 15;
    *(float4*)&s_a[d*68 + 4*jq] = *(const float4*)&wself[d*64 + 4*jq];
    *(float4*)&s_b[d*68 + 4*jq] = *(const float4*)&wnb[d*64 + 4*jq];
  }
  __syncthreads();
  int ty = tid >> 4, tx = tid & 15;
  float acc0[4][4], acc1[4][4];
  #pragma unroll
  for (int i = 0; i < 4; ++i)
    #pragma unroll
    for (int j = 0; j < 4; ++j) { acc0[i][j] = 0.f; acc1[i][j] = 0.f; }
  #pragma unroll 8
  for (int d = 0; d < 64; ++d) {
    float4 av = *(const float4*)&s_tT[d*68 + 4*ty];
    float4 b1 = *(const float4*)&s_a[d*68 + 4*tx];
    float4 b2 = *(const float4*)&s_b[d*68 + 4*tx];
    float a[4] = {av.x, av.y, av.z, av.w};
    float u[4] = {b1.x, b1.y, b1.z, b1.w};
    float w[4] = {b2.x, b2.y, b2.z, b2.w};
    #pragma unroll
    for (int i = 0; i < 4; ++i)
      #pragma unroll
      for (int j = 0; j < 4; ++j) { acc0[i][j] += a[i]*u[j]; acc1[i][j] += a[i]*w[j]; }
  }
  #pragma unroll
  for (int i = 0; i < 4; ++i) {
    int n = n0 + 4*ty + i;
    if (n < 729) {
      size_t o = ((size_t)b * 729 + n) * 64 + 4*tx;
      *(float4*)&hs[o] = make_float4(acc0[i][0], acc0[i][1], acc0[i][2], acc0[i][3]);
      *(float4*)&hw[o] = make_float4(acc1[i][0], acc1[i][1], acc1[i][2], acc1[i][3]);
    }
  }
}

// ---------------------------------------------------------------------------
// kNN v3 (from R8): 2x8 register tile, register top-8, double-buffered
// m-tiles, 1 barrier/tile. Ranking: (xx[m]-2*dot, idx) lexicographic.
// ---------------------------------------------------------------------------
__global__ __launch_bounds__(256) void dist_topk(
    const float* __restrict__ t, const float* __restrict__ xx, int* __restrict__ nbr)
{
  int lb = (blockIdx.x & 7) * 96 + (blockIdx.x >> 3);
  int b = lb / 12, nt = lb % 12, n0 = nt * 64;
  __shared__ __align__(16) float s_nT[64 * 68];
  __shared__ __align__(16) float s_m0[64 * 68];
  __shared__ __align__(16) float s_m1[64 * 68];

  const int tid = threadIdx.x;
  const int rg = tid >> 3;            // 0..31 -> rows 2rg, 2rg+1
  const int cg = tid & 7;             // cols 8cg..8cg+7
  const int r0 = 2 * rg, r1 = r0 + 1;
  const int self0 = n0 + r0, self1 = n0 + r1;
  const size_t tb = (size_t)b * 729;
  const float* xxb = &xx[b * 729];

  float kv0[8], kv1[8]; int ki0[8], ki1[8];
  #pragma unroll
  for (int i = 0; i < 8; ++i) {
    kv0[i] = 3.0e38f; ki0[i] = 0x7fffffff;
    kv1[i] = 3.0e38f; ki1[i] = 0x7fffffff;
  }

  for (int i = tid; i < 1024; i += 256) {
    int n = i >> 4, dq = i & 15;
    float4 v = make_float4(0.f, 0.f, 0.f, 0.f);
    if (n0 + n < 729) v = *(const float4*)&t[(tb + n0 + n) * 64 + 4 * dq];
    s_nT[(4*dq+0)*68 + n] = v.x;
    s_nT[(4*dq+1)*68 + n] = v.y;
    s_nT[(4*dq+2)*68 + n] = v.z;
    s_nT[(4*dq+3)*68 + n] = v.w;
  }
  for (int i = tid; i < 1024; i += 256) {
    int m = i >> 4, dq = i & 15;
    float4 v = *(const float4*)&t[(tb + m) * 64 + 4 * dq];
    s_m0[(4*dq+0)*68 + m] = v.x;
    s_m0[(4*dq+1)*68 + m] = v.y;
    s_m0[(4*dq+2)*68 + m] = v.z;
    s_m0[(4*dq+3)*68 + m] = v.w;
  }
  __syncthreads();

  for (int mt = 0; mt < 12; ++mt) {
    const int m0 = mt * 64;
    const float* cur = (mt & 1) ? s_m1 : s_m0;
    float*       nxt = (mt & 1) ? s_m0 : s_m1;

    float4 st[4];
    if (mt < 11) {
      #pragma unroll
      for (int j = 0; j < 4; ++j) {
        int i = tid + 256 * j; int m = i >> 4, dq = i & 15;
        int mm = m0 + 64 + m;
        st[j] = (mm < 729) ? *(const float4*)&t[(tb + mm) * 64 + 4 * dq]
                           : make_float4(0.f, 0.f, 0.f, 0.f);
      }
    }
    float xm[8];
    #pragma unroll
    for (int k = 0; k < 8; ++k) {
      // reads past 729 stay inside ws and are filtered by the m<729 check
      xm[k] = xxb[m0 + 8*cg + k];
    }

    float acc0[8], acc1[8];
    #pragma unroll
    for (int j = 0; j < 8; ++j) { acc0[j] = 0.f; acc1[j] = 0.f; }
    #pragma unroll 4
    for (int d = 0; d < 64; ++d) {
      float2 a  = *(const float2*)&s_nT[d*68 + r0];
      float4 bA = *(const float4*)&cur[d*68 + 8*cg];
      float4 bB = *(const float4*)&cur[d*68 + 8*cg + 4];
      float bb[8] = {bA.x, bA.y, bA.z, bA.w, bB.x, bB.y, bB.z, bB.w};
      #pragma unroll
      for (int j = 0; j < 8; ++j) {
        acc0[j] += a.x * bb[j];
        acc1[j] += a.y * bb[j];
      }
    }

    #pragma unroll
    for (int k = 0; k < 8; ++k) {
      int m = m0 + 8*cg + k;
      bool inb = (m < 729);
      {
        float sv = fmaf(-2.f, acc0[k], xm[k]);
        bool lt = inb && (m != self0) &&
                  ((sv < kv0[7]) || (sv == kv0[7] && m < ki0[7]));
        if (lt) {
          float cv = sv; int ci = m;
          #pragma unroll
          for (int ii = 0; ii < 8; ++ii) {
            bool less = (cv < kv0[ii]) || (cv == kv0[ii] && ci < ki0[ii]);
            float tv = less ? kv0[ii] : cv; int ti = less ? ki0[ii] : ci;
            kv0[ii] = less ? cv : kv0[ii]; ki0[ii] = less ? ci : ki0[ii];
            cv = tv; ci = ti;
          }
        }
      }
      {
        float sv = fmaf(-2.f, acc1[k], xm[k]);
        bool lt = inb && (m != self1) &&
                  ((sv < kv1[7]) || (sv == kv1[7] && m < ki1[7]));
        if (lt) {
          float cv = sv; int ci = m;
          #pragma unroll
          for (int ii = 0; ii < 8; ++ii) {
            bool less = (cv < kv1[ii]) || (cv == kv1[ii] && ci < ki1[ii]);
            float tv = less ? kv1[ii] : cv; int ti = less ? ki1[ii] : ci;
            kv1[ii] = less ? cv : kv1[ii]; ki1[ii] = less ? ci : ki1[ii];
            cv = tv; ci = ti;
          }
        }
      }
    }

    if (mt < 11) {
      #pragma unroll
      for (int j = 0; j < 4; ++j) {
        int i = tid + 256 * j; int m = i >> 4, dq = i & 15;
        nxt[(4*dq+0)*68 + m] = st[j].x;
        nxt[(4*dq+1)*68 + m] = st[j].y;
        nxt[(4*dq+2)*68 + m] = st[j].z;
        nxt[(4*dq+3)*68 + m] = st[j].w;
      }
    }
    __syncthreads();
  }

  float* mv = s_m0;
  int*   mi = (int*)s_m1;
  #pragma unroll
  for (int k = 0; k < 8; ++k) {
    mv[r0*68 + cg*8 + k] = kv0[k]; mi[r0*68 + cg*8 + k] = ki0[k];
    mv[r1*68 + cg*8 + k] = kv1[k]; mi[r1*68 + cg*8 + k] = ki1[k];
  }
  __syncthreads();
  if (tid < 64) {
    int n = n0 + tid;
    if (n < 729) {
      int rb = tid * 68;
      int p[8] = {0,0,0,0,0,0,0,0};
      int* op = &nbr[((size_t)b * 729 + n) * 8];
      for (int o = 0; o < 8; ++o) {
        float bvv = 3.5e38f; int bii = 0x7fffffff; int bq = 0;
        #pragma unroll
        for (int q = 0; q < 8; ++q) {
          float v = mv[rb + q*8 + p[q]]; int ii = mi[rb + q*8 + p[q]];
          if (v < bvv || (v == bvv && ii < bii)) { bvv = v; bii = ii; bq = q; }
        }
        #pragma unroll
        for (int q = 0; q < 8; ++q) p[q] += (bq == q);
        op[o] = bii;
      }
    }
  }
}

// ---------------------------------------------------------------------------
__global__ __launch_bounds__(256) void gkan_kernel(
    const float* __restrict__ hs, const float* __restrict__ hw,
    const int* __restrict__ nbr, const float* __restrict__ bias,
    const float* __restrict__ kan_a, const float* __restrict__ kan_b,
    float* __restrict__ gpre)
{
  int row = blockIdx.x * 4 + (threadIdx.x >> 6);
  int d = threadIdx.x & 63;
  float degf = 8.0f + 1e-6f;
  float coef = 1.0f / degf;
  size_t bbase = (size_t)(row / 729) * 729;
  float v = hs[(size_t)row * 64 + d] + hw[(size_t)row * 64 + d] + bias[d];
  float nsum = 0.f;
  #pragma unroll
  for (int j = 0; j < 8; ++j) {
    int m = nbr[(size_t)row * 8 + j];
    nsum += hw[(bbase + m) * 64 + d];
  }
  v += coef * nsum;
  float a0 = kan_a[d*3], a1 = kan_a[d*3+1], a2 = kan_a[d*3+2];
  float b0 = kan_b[d*2], b1 = kan_b[d*2+1];
  float v2 = v * v;
  float num = a0 + a1*v + a2*v2;
  float den = 1.f + fabsf(b0*v + b1*v2);
  gpre[(size_t)row * 64 + d] = num / (den + 1e-8f);
}

__global__ __launch_bounds__(256) void stats_tok(
    const float* __restrict__ g, double* __restrict__ stats)
{
  int d = threadIdx.x & 63, qq = threadIdx.x >> 6;
  int r0 = blockIdx.x * 183;
  int rend = r0 + 183; if (rend > NROWS) rend = NROWS;
  float sm = 0.f, sq = 0.f;
  for (int r = r0 + qq; r < rend; r += 4) {
    float v = g[(size_t)r * 64 + d];
    sm += v; sq += v * v;
  }
  __shared__ float ls[256], lq[256];
  ls[threadIdx.x] = sm; lq[threadIdx.x] = sq;
  __syncthreads();
  if (threadIdx.x < 64) {
    sm = ls[d] + ls[64+d] + ls[128+d] + ls[192+d];
    sq = lq[d] + lq[64+d] + lq[128+d] + lq[192+d];
    atomicAdd(&stats[d], (double)sm);
    atomicAdd(&stats[64 + d], (double)sq);
  }
}

// ---------------------------------------------------------------------------
__global__ __launch_bounds__(256) void fuzzy_attn(
    const float* __restrict__ gpre, const float* __restrict__ scshG,
    const float* __restrict__ centers, const float* __restrict__ gam,
    const float* __restrict__ w1, const float* __restrict__ b1,
    const float* __restrict__ w2, const float* __restrict__ b2,
    float* __restrict__ g2)
{
  int wv = threadIdx.x >> 6, d = threadIdx.x & 63;
  int row = blockIdx.x * 4 + wv;
  __shared__ float s_rbf[4][64];
  __shared__ float s_a1[4][16];
  float v = gpre[(size_t)row * 64 + d];
  float gn = fmaf(v, scshG[d], scshG[64 + d]);
  float acc = 0.f;
  #pragma unroll
  for (int f = 0; f < 9; ++f) {
    float dc = gn - centers[d*9 + f];
    acc += expf(-fabsf(gam[d*9 + f]) * dc * dc);
  }
  s_rbf[wv][d] = acc + 9e-10f;
  __syncthreads();
  if (d < 16) {
    float a = b1[d];
    #pragma unroll 8
    for (int k = 0; k < 64; ++k) a += w1[d*64 + k] * s_rbf[wv][k];
    s_a1[wv][d] = fmaxf(a, 0.f);
  }
  __syncthreads();
  float a2 = b2[d];
  #pragma unroll
  for (int i = 0; i < 16; ++i) a2 += w2[d*16 + i] * s_a1[wv][i];
  float sig = 1.f / (1.f + expf(-a2));
  g2[(size_t)row * 64 + d] = gn * (1.f + sig);
}

__global__ __launch_bounds__(256) void pool_kernel(
    const float* __restrict__ g2, const float* __restrict__ scshF, float* __restrict__ p)
{
  int b = blockIdx.x;
  int d = threadIdx.x & 63, qq = threadIdx.x >> 6;
  float sc = scshF[d], sh = scshF[64 + d];
  float sm = 0.f, mx = -3.0e38f;
  for (int n = qq; n < 729; n += 4) {
    float v = fmaf(g2[((size_t)b * 729 + n) * 64 + d], sc, sh);
    sm += v; mx = fmaxf(mx, v);
  }
  __shared__ float ls[256], lm[256];
  ls[threadIdx.x] = sm; lm[threadIdx.x] = mx;
  __syncthreads();
  if (threadIdx.x < 64) {
    sm = ls[d] + ls[64+d] + ls[128+d] + ls[192+d];
    mx = fmaxf(fmaxf(lm[d], lm[64+d]), fmaxf(lm[128+d], lm[192+d]));
    p[b * 64 + d] = 0.5f * (sm / 729.f) + 0.5f * mx;
  }
}

__global__ __launch_bounds__(256) void classifier(
    const float* __restrict__ p, const float* __restrict__ f1w, const float* __restrict__ f1b,
    const float* __restrict__ bng, const float* __restrict__ bnb,
    const float* __restrict__ f2w, const float* __restrict__ f2b, float* __restrict__ outp)
{
  __shared__ float s_p[64 * 64];
  __shared__ float s_c[64 * 128];
  __shared__ float s_sc[128], s_sh[128];
  for (int i = threadIdx.x; i < 4096; i += 256) s_p[i] = p[i];
  __syncthreads();
  for (int o = threadIdx.x; o < 8192; o += 256) {
    int b = o >> 7, h = o & 127;
    float acc = f1b[h];
    #pragma unroll 8
    for (int d = 0; d < 64; ++d) acc += s_p[b*64 + d] * f1w[h*64 + d];
    s_c[o] = acc;
  }
  __syncthreads();
  if (threadIdx.x < 128) {
    int h = threadIdx.x;
    float sm = 0.f, sq = 0.f;
    for (int b = 0; b < 64; ++b) { float v = s_c[b*128 + h]; sm += v; sq += v*v; }
    float mu = sm / 64.f;
    float var = sq / 64.f - mu * mu;
    float rstd = rsqrtf(var + 1e-5f);
    float sc = bng[h] * rstd;
    s_sc[h] = sc; s_sh[h] = bnb[h] - mu * sc;
  }
  __syncthreads();
  for (int o = threadIdx.x; o < 1024; o += 256) {
    int b = o >> 4, j = o & 15;
    float acc = f2b[j];
    #pragma unroll 8
    for (int h = 0; h < 128; ++h) {
      float v = fmaxf(fmaf(s_c[b*128 + h], s_sc[h], s_sh[h]), 0.f);
      acc += f2w[j*128 + h] * v;
    }
    outp[o] = acc;
  }
}

// ---------------------------------------------------------------------------
extern "C" void kernel_launch(void* const* d_in, const int* in_sizes, int n_in,
                              void* d_out, int out_size, void* d_ws, size_t ws_size,
                              hipStream_t stream)
{
  const float* x      = (const float*)d_in[0];
  const float* c1w    = (const float*)d_in[1];
  const float* c1b    = (const float*)d_in[2];
  const float* bn1g   = (const float*)d_in[3];
  const float* bn1b   = (const float*)d_in[4];
  const float* c2wt   = (const float*)d_in[5];
  const float* c2b    = (const float*)d_in[6];
  const float* bn2g   = (const float*)d_in[7];
  const float* bn2b   = (const float*)d_in[8];
  const float* c3wt   = (const float*)d_in[9];
  const float* c3b    = (const float*)d_in[10];
  const float* bn3g   = (const float*)d_in[11];
  const float* bn3b   = (const float*)d_in[12];
  const float* wself  = (const float*)d_in[13];
  const float* wnb    = (const float*)d_in[14];
  const float* gbias  = (const float*)d_in[15];
  const float* kana   = (const float*)d_in[16];
  const float* kanb   = (const float*)d_in[17];
  const float* gbng   = (const float*)d_in[18];
  const float* gbnb   = (const float*)d_in[19];
  const float* cent   = (const float*)d_in[20];
  const float* gamr   = (const float*)d_in[21];
  const float* aw1    = (const float*)d_in[22];
  const float* ab1    = (const float*)d_in[23];
  const float* aw2    = (const float*)d_in[24];
  const float* ab2    = (const float*)d_in[25];
  const float* fbng   = (const float*)d_in[26];
  const float* fbnb   = (const float*)d_in[27];
  const float* f1w    = (const float*)d_in[28];
  const float* f1b    = (const float*)d_in[29];
  const float* cbng   = (const float*)d_in[30];
  const float* cbnb   = (const float*)d_in[31];
  const float* f2w    = (const float*)d_in[32];
  const float* f2b    = (const float*)d_in[33];

  // Adaptive layout: big path enlarges P to 47.78MB -> conv1 8 slabs,
  // conv2/3 4 slabs -> grid 1024 everywhere (4 blocks/CU).
  const size_t BIG_NEED = 79338496;   // P 47.78M + c1..c3 + nbr + xx + small
  const bool big = (ws_size >= BIG_NEED);

  char* ws = (char*)d_ws;
  size_t Psz = big ? 47775744u : 23887872u;
  float*  P     = (float*) (ws + 0);
  float*  c1    = (float*) (ws + Psz);
  float*  c2    = (float*) (ws + Psz + 5971968);
  float*  c3    = (float*) (ws + Psz + 17915904);
  int*    nbr   = (int*)   (ws + Psz + 29859840);
  float*  xx    = (float*) (ws + Psz + 31352832);
  double* stats = (double*)(ws + Psz + 31539456);
  float*  scsh  = (float*) (ws + Psz + 31544064);
  float*  pbuf  = (float*) (ws + Psz + 31546368);
  // aliases (disjoint lifetimes on the serialized stream):
  float* hw   = P;                       // gemm output, after conv reduces consumed P
  float* t    = (float*)(ws + 11943936); // inside P, after P dead
  float* hs   = c2;                      // after conv3 consumed c2
  float* gpre = c3;                      // after transpose consumed c3
  float* g2   = t;                       // after gemm+dist consumed t

  const int ns1 = big ? 8 : 4, cps1 = big ? 25 : 50;   // conv1: Cin=200
  const int ns2 = big ? 4 : 2, cps2 = big ? 8  : 16;   // conv2: Cin=32
  const int ns3 = big ? 4 : 2, cps3 = big ? 16 : 32;   // conv3: Cin=64
  const int g1 = 2 * ns1 * 64;   // bigGroups(32/16)=2
  const int g2r = 4 * ns2 * 64;  // bigGroups(64/16)=4
  const int g3 = 4 * ns3 * 64;

  hipMemsetAsync(stats, 0, 576 * sizeof(double), stream);

  const float inv = 1.0f / 46656.0f;

  conv3x3_v6<8,false><<<dim3(g1), dim3(256), 0, stream>>>(
      x,  c1w, nullptr, P, 200, 32, cps1, ns1);
  conv_reduce_stats<<<dim3(2048), dim3(256), 0, stream>>>(P, c1b, c1, stats, 32, ns1);
  bn_finalize<<<dim3(1), dim3(32), 0, stream>>>(stats, bn1g, bn1b, scsh, 32, inv);
  conv3x3_v6<8,true><<<dim3(g2r), dim3(256), 0, stream>>>(
      c1, c2wt, scsh, P, 32, 64, cps2, ns2);
  conv_reduce_stats<<<dim3(4096), dim3(256), 0, stream>>>(P, c2b, c2, stats + 64, 64, ns2);
  bn_finalize<<<dim3(1), dim3(64), 0, stream>>>(stats + 64, bn2g, bn2b, scsh + 64, 64, inv);
  conv3x3_v6<8,true><<<dim3(g3), dim3(256), 0, stream>>>(
      c2, c3wt, scsh + 64, P, 64, 64, cps3, ns3);
  conv_reduce_stats<<<dim3(4096), dim3(256), 0, stream>>>(P, c3b, c3, stats + 192, 64, ns3);
  bn_finalize<<<dim3(1), dim3(64), 0, stream>>>(stats + 192, bn3g, bn3b, scsh + 192, 64, inv);
  // tokens
  bn_transpose_xx<<<dim3(768), dim3(256), 0, stream>>>(c3, scsh + 192, t, xx);
  gemm_selfnb<<<dim3(768), dim3(256), 0, stream>>>(t, wself, wnb, hs, hw);
  dist_topk<<<dim3(768), dim3(256), 0, stream>>>(t, xx, nbr);
  gkan_kernel<<<dim3(11664), dim3(256), 0, stream>>>(hs, hw, nbr, gbias, kana, kanb, gpre);
  stats_tok<<<dim3(256), dim3(256), 0, stream>>>(gpre, stats + 320);
  bn_finalize<<<dim3(1), dim3(64), 0, stream>>>(stats + 320, gbng, gbnb, scsh + 320, 64, inv);
  fuzzy_attn<<<dim3(11664), dim3(256), 0, stream>>>(gpre, scsh + 320, cent, gamr, aw1, ab1, aw2, ab2, g2);
  stats_tok<<<dim3(256), dim3(256), 0, stream>>>(g2, stats + 448);
  bn_finalize<<<dim3(1), dim3(64), 0, stream>>>(stats + 448, fbng, fbnb, scsh + 448, 64, inv);
  pool_kernel<<<dim3(64), dim3(256), 0, stream>>>(g2, scsh + 448, pbuf);
  classifier<<<dim3(1), dim3(256), 0, stream>>>(pbuf, f1w, f1b, cbng, cbnb, f2w, f2b, (float*)d_out);
}